// Round 9
// baseline (941.956 us; speedup 1.0000x reference)
//
#include <hip/hip_runtime.h>

#define BATCH 4
#define SLEN 4096
#define DDIM 512
#define GDIM 64
#define NORIG 4096
#define WMAX 15            // d = 1..15 (window_size 16)
#define RSEL 1024
#define KEEP (SLEN - RSEL) // 3072
#define NTOK (BATCH * SLEN)
#define PEEL_ROUNDS 256

// ---- workspace layout (bytes) ----
// gn region [0, 8.4MB) is dead after k_sims -> reuse for taken-pair scratch.
#define OFF_TCODE ((size_t)0)            // u16    [B][2048]    = 16,384   (reuses gn)
#define OFF_TCNT  ((size_t)16384)        // int    [B]          = 16       (reuses gn)
#define OFF_GN    ((size_t)0)            // double [B][S][G]    = 8,388,608
#define OFF_SIMST ((size_t)8388608)      // double [B][S][16]   = 2,097,152  (slot d=1..15)
#define OFF_NORMS ((size_t)10485760)     // float  [B][S]       = 65,536
#define OFF_BEST0 ((size_t)10551296)     // u16    [B][S]       = 32,768
#define OFF_KT    ((size_t)10584064)     // int    [B][KEEP]    = 49,152
#define OFF_PJR   ((size_t)10633216)     // int    [B][KEEP]
#define OFF_WIR   ((size_t)10682368)     // float  [B][KEEP]
#define OFF_WJR   ((size_t)10731520)     // float  [B][KEEP]
#define WS_NEEDED ((size_t)10780672)

// ---- output layout (f32 elements) ----
#define OUTX_OFF 0
#define OUTS_OFF 6291456          // 4*3072*512
#define OUTP_OFF 56623104         // + 4*3072*4096

// Best alive incident pair for token t. HAND-UNROLLED straight-line code (no
// unroller involvement — compile-time safety): 30 clamped loads up-front (ILP),
// then the strict-total-order compare chain (sim desc, i asc, d asc). Result is
// the unique max under that order => enumeration-order independent.
template <bool FILTER>
__device__ __forceinline__ unsigned short best_code(const double* __restrict__ simsT,
                                                    const unsigned char* used, int t) {
#define BC_LOAD(d) \
  const double sR##d = simsT[(size_t)t * 16 + d]; \
  const double sL##d = simsT[(size_t)max(t - d, 0) * 16 + d]; \
  const bool vR##d = (t + d < SLEN) && (!FILTER || !used[min(t + d, SLEN - 1)]); \
  const bool vL##d = (t >= d) && (!FILTER || !used[max(t - d, 0)]);
  BC_LOAD(1) BC_LOAD(2) BC_LOAD(3) BC_LOAD(4) BC_LOAD(5)
  BC_LOAD(6) BC_LOAD(7) BC_LOAD(8) BC_LOAD(9) BC_LOAD(10)
  BC_LOAD(11) BC_LOAD(12) BC_LOAD(13) BC_LOAD(14) BC_LOAD(15)
#undef BC_LOAD
  double bs = 0.0; int bi = -1, bd = 0;
#define BC_CMP(d) \
  if (vR##d && (bi < 0 || sR##d > bs || (sR##d == bs && (t < bi || (t == bi && d < bd))))) { bs = sR##d; bi = t; bd = d; } \
  if (vL##d && (bi < 0 || sL##d > bs || (sL##d == bs && ((t - d) < bi || ((t - d) == bi && d < bd))))) { bs = sL##d; bi = t - d; bd = d; }
  BC_CMP(1) BC_CMP(2) BC_CMP(3) BC_CMP(4) BC_CMP(5)
  BC_CMP(6) BC_CMP(7) BC_CMP(8) BC_CMP(9) BC_CMP(10)
  BC_CMP(11) BC_CMP(12) BC_CMP(13) BC_CMP(14) BC_CMP(15)
#undef BC_CMP
  return (bi >= 0) ? (unsigned short)((bi << 4) | bd) : (unsigned short)0xFFFFu;
}

// K1: g = x@W in f64, norms, gn = g/max(norm,1e-12).
__global__ __launch_bounds__(256) void k_proj(const float* __restrict__ x,
                                              const float* __restrict__ Wm,
                                              double* __restrict__ gn,
                                              float* __restrict__ norms) {
  __shared__ float xs[16 * DDIM];
  int base = blockIdx.x * 16;
  const float4* src = (const float4*)(x + (size_t)base * DDIM);
  float4* dstv = (float4*)xs;
  for (int idx = threadIdx.x; idx < 16 * DDIM / 4; idx += 256) dstv[idx] = src[idx];
  __syncthreads();
  int lane = threadIdx.x & 63;
  int wv = threadIdx.x >> 6;
  double acc0 = 0, acc1 = 0, acc2 = 0, acc3 = 0;
  const float* xw = xs + wv * 4 * DDIM;
  for (int d = 0; d < DDIM; ++d) {
    double wval = (double)Wm[d * GDIM + lane];
    acc0 += (double)xw[d] * wval;
    acc1 += (double)xw[DDIM + d] * wval;
    acc2 += (double)xw[2 * DDIM + d] * wval;
    acc3 += (double)xw[3 * DDIM + d] * wval;
  }
  double accs[4] = {acc0, acc1, acc2, acc3};
  for (int k = 0; k < 4; ++k) {
    double a = accs[k];
    double ss = a * a;
    for (int o = 32; o >= 1; o >>= 1) ss += __shfl_xor(ss, o, 64);
    double nrm = sqrt(ss);
    int tok = base + wv * 4 + k;
    if (lane == 0) norms[tok] = (float)nrm;
    double denom = nrm > 1e-12 ? nrm : 1e-12;
    gn[(size_t)tok * GDIM + lane] = a / denom;
  }
}

// K2: sims for pairs (i, i+d), token-major: simsT[(b*S+i)*16 + d].
__global__ __launch_bounds__(256) void k_sims(const double* __restrict__ gn,
                                              double* __restrict__ simsT) {
  int blk = blockIdx.x;
  int b = blk >> 6;
  int t0 = (blk & 63) * 64;
  int nrows = min(64 + WMAX, SLEN - t0);
  __shared__ double gs[(64 + WMAX) * GDIM];
  const double* src = gn + ((size_t)b * SLEN + t0) * GDIM;
  for (int idx = threadIdx.x; idx < nrows * GDIM; idx += 256) gs[idx] = src[idx];
  __syncthreads();
  int lane = threadIdx.x & 63, wv = threadIdx.x >> 6;
  for (int s = wv; s < 64 * WMAX; s += 4) {
    int il = s & 63, d = (s >> 6) + 1;
    int i = t0 + il;
    if (i + d < SLEN) {
      double p = gs[il * GDIM + lane] * gs[(il + d) * GDIM + lane];
      for (int o = 32; o >= 1; o >>= 1) p += __shfl_xor(p, o, 64);
      if (lane == 0) simsT[((size_t)(b * SLEN + i)) * 16 + d] = p;
    }
  }
}

// K2b: initial best incident pair per token, full-GPU parallel.
__global__ __launch_bounds__(256) void k_best0(const double* __restrict__ simsT,
                                               unsigned short* __restrict__ best0) {
  int t = blockIdx.x * 256 + threadIdx.x;
  int b = t >> 12, tt = t & (SLEN - 1);
  best0[t] = best_code<false>(simsT + (size_t)b * SLEN * 16, nullptr, tt);
}

// K3a: per-batch PEEL ONLY (instrumentation split). Mutual-best pair peeling ==
// sequential greedy under the strict total order. Writes taken codes + count.
__global__ __launch_bounds__(1024) void k_peel(const double* __restrict__ simsT_all,
                                               const unsigned short* __restrict__ best0,
                                               unsigned short* __restrict__ tcodeG,
                                               int* __restrict__ tcntG) {
  int b = blockIdx.x;
  const double* simsT = simsT_all + (size_t)b * SLEN * 16;
  __shared__ unsigned short bestPair[SLEN];
  __shared__ unsigned char used[SLEN];
  __shared__ unsigned char dirty[SLEN];
  __shared__ unsigned short takenCode[2048];
  __shared__ int takenCnt, baseCnt;
  int tid = threadIdx.x;
#pragma clang loop unroll(disable)
  for (int t = tid; t < SLEN; t += 1024) {
    used[t] = 0; dirty[t] = 0;
    bestPair[t] = best0[b * SLEN + t];
  }
  if (tid == 0) takenCnt = 0;
  __syncthreads();

#pragma clang loop unroll(disable)
  for (int round = 0; round < PEEL_ROUNDS; ++round) {
    if (tid == 0) baseCnt = takenCnt;
    __syncthreads();
#pragma clang loop unroll(disable)
    for (int t = tid; t < SLEN; t += 1024) {
      unsigned short c = bestPair[t];
      if (c != 0xFFFFu && (c >> 4) == t) {
        int j = t + (c & 15);
        if (bestPair[j] == c) {
          int idx = atomicAdd(&takenCnt, 1);
          if (idx < 2048) takenCode[idx] = c;
          used[t] = 1; used[j] = 1;
        }
      }
    }
    __syncthreads();
    int newCnt = takenCnt;
    if (newCnt == baseCnt) break;
#pragma clang loop unroll(disable)
    for (int k = baseCnt + tid; k < newCnt && k < 2048; k += 1024) {
      int c = takenCode[k];
      int i = c >> 4, j = i + (c & 15);
      bestPair[i] = 0xFFFFu; bestPair[j] = 0xFFFFu;
      int lo = max(i - WMAX, 0), hi = min(j + WMAX, SLEN - 1);
#pragma clang loop unroll(disable)
      for (int t = lo; t <= hi; ++t) if (!used[t]) dirty[t] = 1;
    }
    __syncthreads();
#pragma clang loop unroll(disable)
    for (int t = tid; t < SLEN; t += 1024) {
      if (dirty[t]) { dirty[t] = 0; bestPair[t] = best_code<true>(simsT, used, t); }
    }
    __syncthreads();
  }

  int m = min(takenCnt, 2048);
#pragma clang loop unroll(disable)
  for (int k = tid; k < m; k += 1024) tcodeG[b * 2048 + k] = takenCode[k];
  if (tid == 0) tcntG[b] = m;
}

// K3b: selection (top-r of taken pairs by (sim desc, i asc, d asc)) via 256-bucket
// histogram select on sortable-u64-packed f64 keys; exact rank only inside the unique
// straddling bucket. Then compaction + per-row metadata + pos output (r8-identical).
__global__ __launch_bounds__(1024) void k_rank(const double* __restrict__ simsT_all,
                                               const unsigned short* __restrict__ tcodeG,
                                               const int* __restrict__ tcntG,
                                               const float* __restrict__ norms,
                                               int* __restrict__ kt, int* __restrict__ pjr,
                                               float* __restrict__ wir, float* __restrict__ wjr,
                                               float* __restrict__ out_pos) {
  int b = blockIdx.x;
  const double* simsT = simsT_all + (size_t)b * SLEN * 16;
  __shared__ unsigned short code[2048];
  __shared__ unsigned long long key[2048];
  __shared__ unsigned int hist[256];
  __shared__ unsigned int bcum[256];          // # pairs in strictly-better buckets
  __shared__ unsigned short memberIdx[2048];
  __shared__ int memberCnt;
  __shared__ unsigned char skipA[SLEN];
  __shared__ unsigned char mergeD[SLEN];
  __shared__ int wTot[16], wOff[16];
  int tid = threadIdx.x;
  int m = min(tcntG[b], 2048);
#pragma clang loop unroll(disable)
  for (int t = tid; t < SLEN; t += 1024) { skipA[t] = 0; mergeD[t] = 0; }
  if (tid < 256) hist[tid] = 0;
  if (tid == 0) memberCnt = 0;
  __syncthreads();
#pragma clang loop unroll(disable)
  for (int k = tid; k < m; k += 1024) {
    unsigned short c = tcodeG[b * 2048 + k];
    code[k] = c;
    double s = simsT[(size_t)(c >> 4) * 16 + (c & 15)];
    unsigned long long bits = (unsigned long long)__double_as_longlong(s);
    unsigned long long ky = (bits & 0x8000000000000000ULL) ? ~bits : (bits | 0x8000000000000000ULL);
    key[k] = ky;                                  // u64 compare == f64 compare
    atomicAdd(&hist[(unsigned int)(ky >> 56)], 1u);
  }
  __syncthreads();
  if (tid == 0) {
    unsigned int acc = 0;
#pragma clang loop unroll(disable)
    for (int bkt = 255; bkt >= 0; --bkt) { bcum[bkt] = acc; acc += hist[bkt]; }
  }
  __syncthreads();
  // classify: whole-bucket accept/reject; straddling bucket -> member list
#pragma clang loop unroll(disable)
  for (int k = tid; k < m; k += 1024) {
    unsigned int bkt = (unsigned int)(key[k] >> 56);
    unsigned int better = bcum[bkt];
    if (better >= RSEL) continue;                       // rejected
    if (better + hist[bkt] <= RSEL) {                   // fully selected bucket
      unsigned short ck = code[k];
      int i = ck >> 4, d = ck & 15;
      mergeD[i] = (unsigned char)d; skipA[i + d] = 1;
    } else {                                            // straddling bucket member
      int idx = atomicAdd(&memberCnt, 1);
      memberIdx[idx] = (unsigned short)k;
    }
  }
  __syncthreads();
  int mc = memberCnt;
#pragma clang loop unroll(disable)
  for (int z = tid; z < mc; z += 1024) {
    int k = memberIdx[z];
    unsigned int bkt = (unsigned int)(key[k] >> 56);
    unsigned int need = RSEL - bcum[bkt];
    unsigned long long kk = key[k]; unsigned short ck = code[k];
    unsigned int wr = 0;
#pragma clang loop unroll(disable)
    for (int q2 = 0; q2 < mc; ++q2) {
      int q = memberIdx[q2];
      unsigned long long kq = key[q];
      if (kq > kk || (kq == kk && code[q] < ck)) wr++;
    }
    if (wr < need) {
      int i = ck >> 4, d = ck & 15;
      mergeD[i] = (unsigned char)d; skipA[i + d] = 1;
    }
  }
  __syncthreads();
  // compact kept tokens (prefix sum of !skip), 4 contiguous tokens per thread
  int cnt = 0; unsigned char kf[4];
  int tbase = tid * 4;
  for (int u = 0; u < 4; ++u) { kf[u] = skipA[tbase + u] ? 0 : 1; cnt += kf[u]; }
  int lane = tid & 63, wv = tid >> 6;
  int incl = cnt;
  for (int o = 1; o < 64; o <<= 1) { int n = __shfl_up(incl, o, 64); if (lane >= o) incl += n; }
  if (lane == 63) wTot[wv] = incl;
  __syncthreads();
  if (tid < 16) {
    int v2 = wTot[tid];
    for (int o = 1; o < 16; o <<= 1) { int n = __shfl_up(v2, o, 64); if (lane >= o) v2 += n; }
    wOff[tid] = v2 - wTot[tid];
  }
  __syncthreads();
  int pos = wOff[wv] + (incl - cnt);
  for (int u = 0; u < 4; ++u) {
    int t = tbase + u;
    if (kf[u]) {
      if (pos < KEEP) {
        int orow = b * KEEP + pos;
        kt[orow] = t;
        int d = mergeD[t];
        pjr[orow] = d ? (t + d) : -1;
        wir[orow] = norms[b * SLEN + t];
        wjr[orow] = d ? norms[b * SLEN + t + d] : 0.0f;
        out_pos[orow] = (float)(b * SLEN + t);
      }
      pos++;
    }
  }
}

// K4: x output rows (512 f32), weighted merge. Indices clamped: poison can never fault.
__global__ __launch_bounds__(128) void k_gather_x(const float* __restrict__ x,
                                                  const int* __restrict__ kt, const int* __restrict__ pjr,
                                                  const float* __restrict__ wir, const float* __restrict__ wjr,
                                                  float* __restrict__ outx) {
  int orow = blockIdx.x;
  int b = orow / KEEP;
  int t = kt[orow], pj = pjr[orow];
  int gi = min(max(b * SLEN + t, 0), NTOK - 1);
  const float4* xi = (const float4*)(x + (size_t)gi * DDIM);
  float4* o = (float4*)(outx + (size_t)orow * DDIM);
  int c = threadIdx.x;
  float4 v = xi[c];
  if (pj >= 0) {
    int gj = min(b * SLEN + min(pj, SLEN - 1), NTOK - 1);
    const float4* xj = (const float4*)(x + (size_t)gj * DDIM);
    float4 u = xj[c];
    float wi = wir[orow], wj = wjr[orow];
    float inv = 1.0f / (wi + wj + 1e-8f);
    v.x = (wi * v.x + wj * u.x) * inv;
    v.y = (wi * v.y + wj * u.y) * inv;
    v.z = (wi * v.z + wj * u.z) * inv;
    v.w = (wi * v.w + wj * u.w) * inv;
  }
  o[c] = v;
}

// K5: source output rows (4096 f32), plain sum merge — the BW-dominant kernel
__global__ __launch_bounds__(256) void k_gather_s(const float* __restrict__ src,
                                                  const int* __restrict__ kt, const int* __restrict__ pjr,
                                                  float* __restrict__ outs) {
  int orow = blockIdx.x;
  int b = orow / KEEP;
  int t = kt[orow], pj = pjr[orow];
  int gi = min(max(b * SLEN + t, 0), NTOK - 1);
  const float4* si = (const float4*)(src + (size_t)gi * NORIG);
  float4* o = (float4*)(outs + (size_t)orow * NORIG);
  if (pj >= 0) {
    int gj = min(b * SLEN + min(pj, SLEN - 1), NTOK - 1);
    const float4* sj = (const float4*)(src + (size_t)gj * NORIG);
    for (int u = 0; u < 4; ++u) {
      int c = threadIdx.x + u * 256;
      float4 a = si[c], bb = sj[c];
      a.x += bb.x; a.y += bb.y; a.z += bb.z; a.w += bb.w;
      o[c] = a;
    }
  } else {
    for (int u = 0; u < 4; ++u) { int c = threadIdx.x + u * 256; o[c] = si[c]; }
  }
}

extern "C" void kernel_launch(void* const* d_in, const int* in_sizes, int n_in,
                              void* d_out, int out_size, void* d_ws, size_t ws_size,
                              hipStream_t stream) {
  if (ws_size < WS_NEEDED) return;  // fail fast & clean instead of faulting

  const float* x = (const float*)d_in[0];
  const float* source = (const float*)d_in[1];
  // d_in[2] = position_ids (== arange(B*S)); d_in[3] = r (1024); d_in[4] = window_size (16)
  const float* Wm = (const float*)d_in[5];

  char* ws = (char*)d_ws;
  double* gn = (double*)(ws + OFF_GN);
  double* simsT = (double*)(ws + OFF_SIMST);
  float* norms = (float*)(ws + OFF_NORMS);
  unsigned short* best0 = (unsigned short*)(ws + OFF_BEST0);
  unsigned short* tcode = (unsigned short*)(ws + OFF_TCODE);  // reuses gn (dead after k_sims)
  int* tcnt = (int*)(ws + OFF_TCNT);
  int* kt = (int*)(ws + OFF_KT);
  int* pjr = (int*)(ws + OFF_PJR);
  float* wir = (float*)(ws + OFF_WIR);
  float* wjr = (float*)(ws + OFF_WJR);

  float* out = (float*)d_out;
  float* outx = out + OUTX_OFF;
  float* outs = out + OUTS_OFF;
  float* outp = out + OUTP_OFF;

  k_proj<<<(BATCH * SLEN) / 16, 256, 0, stream>>>(x, Wm, gn, norms);
  k_sims<<<BATCH * (SLEN / 64), 256, 0, stream>>>(gn, simsT);
  k_best0<<<NTOK / 256, 256, 0, stream>>>(simsT, best0);
  k_peel<<<BATCH, 1024, 0, stream>>>(simsT, best0, tcode, tcnt);
  k_rank<<<BATCH, 1024, 0, stream>>>(simsT, tcode, tcnt, norms, kt, pjr, wir, wjr, outp);
  k_gather_x<<<BATCH * KEEP, 128, 0, stream>>>(x, kt, pjr, wir, wjr, outx);
  k_gather_s<<<BATCH * KEEP, 256, 0, stream>>>(source, kt, pjr, outs);
}

// Round 10
// 422.011 us; speedup vs baseline: 2.2321x; 2.2321x over previous
//
#include <hip/hip_runtime.h>

#define BATCH 4
#define SLEN 4096
#define DDIM 512
#define GDIM 64
#define NORIG 4096
#define WMAX 15            // d = 1..15 (window_size 16)
#define RSEL 1024
#define KEEP (SLEN - RSEL) // 3072
#define NTOK (BATCH * SLEN)
#define PEEL_ROUNDS 256

// ---- workspace layout (bytes) ----
// gn region [0, 8.4MB) is dead after k_sims -> reuse for taken-pair scratch.
#define OFF_TCODE ((size_t)0)            // u16    [B][2048]    = 16,384   (reuses gn)
#define OFF_TCNT  ((size_t)16384)        // int    [B]          = 16       (reuses gn)
#define OFF_GN    ((size_t)0)            // double [B][S][G]    = 8,388,608
#define OFF_SIMST ((size_t)8388608)      // double [B][S][16]   = 2,097,152  (slot d=1..15)
#define OFF_NORMS ((size_t)10485760)     // float  [B][S]       = 65,536
#define OFF_BEST0 ((size_t)10551296)     // u16    [B][S]       = 32,768
#define OFF_KT    ((size_t)10584064)     // int    [B][KEEP]    = 49,152
#define OFF_PJR   ((size_t)10633216)     // int    [B][KEEP]
#define OFF_WIR   ((size_t)10682368)     // float  [B][KEEP]
#define OFF_WJR   ((size_t)10731520)     // float  [B][KEEP]
#define WS_NEEDED ((size_t)10780672)

// ---- output layout (f32 elements) ----
#define OUTX_OFF 0
#define OUTS_OFF 6291456          // 4*3072*512
#define OUTP_OFF 56623104         // + 4*3072*4096

// Best alive incident pair for token t. HAND-UNROLLED straight-line code (no
// unroller involvement — compile-time safety): 30 clamped loads up-front (ILP),
// then the strict-total-order compare chain (sim desc, i asc, d asc).
template <bool FILTER>
__device__ __forceinline__ unsigned short best_code(const double* __restrict__ simsT,
                                                    const unsigned char* used, int t) {
#define BC_LOAD(d) \
  const double sR##d = simsT[(size_t)t * 16 + d]; \
  const double sL##d = simsT[(size_t)max(t - d, 0) * 16 + d]; \
  const bool vR##d = (t + d < SLEN) && (!FILTER || !used[min(t + d, SLEN - 1)]); \
  const bool vL##d = (t >= d) && (!FILTER || !used[max(t - d, 0)]);
  BC_LOAD(1) BC_LOAD(2) BC_LOAD(3) BC_LOAD(4) BC_LOAD(5)
  BC_LOAD(6) BC_LOAD(7) BC_LOAD(8) BC_LOAD(9) BC_LOAD(10)
  BC_LOAD(11) BC_LOAD(12) BC_LOAD(13) BC_LOAD(14) BC_LOAD(15)
#undef BC_LOAD
  double bs = 0.0; int bi = -1, bd = 0;
#define BC_CMP(d) \
  if (vR##d && (bi < 0 || sR##d > bs || (sR##d == bs && (t < bi || (t == bi && d < bd))))) { bs = sR##d; bi = t; bd = d; } \
  if (vL##d && (bi < 0 || sL##d > bs || (sL##d == bs && ((t - d) < bi || ((t - d) == bi && d < bd))))) { bs = sL##d; bi = t - d; bd = d; }
  BC_CMP(1) BC_CMP(2) BC_CMP(3) BC_CMP(4) BC_CMP(5)
  BC_CMP(6) BC_CMP(7) BC_CMP(8) BC_CMP(9) BC_CMP(10)
  BC_CMP(11) BC_CMP(12) BC_CMP(13) BC_CMP(14) BC_CMP(15)
#undef BC_CMP
  return (bi >= 0) ? (unsigned short)((bi << 4) | bd) : (unsigned short)0xFFFFu;
}

// K1: g = x@W in f64, norms, gn = g/max(norm,1e-12).
__global__ __launch_bounds__(256) void k_proj(const float* __restrict__ x,
                                              const float* __restrict__ Wm,
                                              double* __restrict__ gn,
                                              float* __restrict__ norms) {
  __shared__ float xs[16 * DDIM];
  int base = blockIdx.x * 16;
  const float4* src = (const float4*)(x + (size_t)base * DDIM);
  float4* dstv = (float4*)xs;
  for (int idx = threadIdx.x; idx < 16 * DDIM / 4; idx += 256) dstv[idx] = src[idx];
  __syncthreads();
  int lane = threadIdx.x & 63;
  int wv = threadIdx.x >> 6;
  double acc0 = 0, acc1 = 0, acc2 = 0, acc3 = 0;
  const float* xw = xs + wv * 4 * DDIM;
  for (int d = 0; d < DDIM; ++d) {
    double wval = (double)Wm[d * GDIM + lane];
    acc0 += (double)xw[d] * wval;
    acc1 += (double)xw[DDIM + d] * wval;
    acc2 += (double)xw[2 * DDIM + d] * wval;
    acc3 += (double)xw[3 * DDIM + d] * wval;
  }
  double accs[4] = {acc0, acc1, acc2, acc3};
  for (int k = 0; k < 4; ++k) {
    double a = accs[k];
    double ss = a * a;
    for (int o = 32; o >= 1; o >>= 1) ss += __shfl_xor(ss, o, 64);
    double nrm = sqrt(ss);
    int tok = base + wv * 4 + k;
    if (lane == 0) norms[tok] = (float)nrm;
    double denom = nrm > 1e-12 ? nrm : 1e-12;
    gn[(size_t)tok * GDIM + lane] = a / denom;
  }
}

// K2: sims for pairs (i, i+d), token-major: simsT[(b*S+i)*16 + d].
__global__ __launch_bounds__(256) void k_sims(const double* __restrict__ gn,
                                              double* __restrict__ simsT) {
  int blk = blockIdx.x;
  int b = blk >> 6;
  int t0 = (blk & 63) * 64;
  int nrows = min(64 + WMAX, SLEN - t0);
  __shared__ double gs[(64 + WMAX) * GDIM];
  const double* src = gn + ((size_t)b * SLEN + t0) * GDIM;
  for (int idx = threadIdx.x; idx < nrows * GDIM; idx += 256) gs[idx] = src[idx];
  __syncthreads();
  int lane = threadIdx.x & 63, wv = threadIdx.x >> 6;
  for (int s = wv; s < 64 * WMAX; s += 4) {
    int il = s & 63, d = (s >> 6) + 1;
    int i = t0 + il;
    if (i + d < SLEN) {
      double p = gs[il * GDIM + lane] * gs[(il + d) * GDIM + lane];
      for (int o = 32; o >= 1; o >>= 1) p += __shfl_xor(p, o, 64);
      if (lane == 0) simsT[((size_t)(b * SLEN + i)) * 16 + d] = p;
    }
  }
}

// K2b: initial best incident pair per token, full-GPU parallel.
__global__ __launch_bounds__(256) void k_best0(const double* __restrict__ simsT,
                                               unsigned short* __restrict__ best0) {
  int t = blockIdx.x * 256 + threadIdx.x;
  int b = t >> 12, tt = t & (SLEN - 1);
  best0[t] = best_code<false>(simsT + (size_t)b * SLEN * 16, nullptr, tt);
}

// K3a: per-batch PEEL ONLY. Mutual-best pair peeling == sequential greedy under the
// strict total order. Writes taken codes + count.
__global__ __launch_bounds__(1024) void k_peel(const double* __restrict__ simsT_all,
                                               const unsigned short* __restrict__ best0,
                                               unsigned short* __restrict__ tcodeG,
                                               int* __restrict__ tcntG) {
  int b = blockIdx.x;
  const double* simsT = simsT_all + (size_t)b * SLEN * 16;
  __shared__ unsigned short bestPair[SLEN];
  __shared__ unsigned char used[SLEN];
  __shared__ unsigned char dirty[SLEN];
  __shared__ unsigned short takenCode[2048];
  __shared__ int takenCnt, baseCnt;
  int tid = threadIdx.x;
#pragma clang loop unroll(disable)
  for (int t = tid; t < SLEN; t += 1024) {
    used[t] = 0; dirty[t] = 0;
    bestPair[t] = best0[b * SLEN + t];
  }
  if (tid == 0) takenCnt = 0;
  __syncthreads();

#pragma clang loop unroll(disable)
  for (int round = 0; round < PEEL_ROUNDS; ++round) {
    if (tid == 0) baseCnt = takenCnt;
    __syncthreads();
#pragma clang loop unroll(disable)
    for (int t = tid; t < SLEN; t += 1024) {
      unsigned short c = bestPair[t];
      if (c != 0xFFFFu && (c >> 4) == t) {
        int j = t + (c & 15);
        if (bestPair[j] == c) {
          int idx = atomicAdd(&takenCnt, 1);
          if (idx < 2048) takenCode[idx] = c;
          used[t] = 1; used[j] = 1;
        }
      }
    }
    __syncthreads();
    int newCnt = takenCnt;
    if (newCnt == baseCnt) break;
#pragma clang loop unroll(disable)
    for (int k = baseCnt + tid; k < newCnt && k < 2048; k += 1024) {
      int c = takenCode[k];
      int i = c >> 4, j = i + (c & 15);
      bestPair[i] = 0xFFFFu; bestPair[j] = 0xFFFFu;
      int lo = max(i - WMAX, 0), hi = min(j + WMAX, SLEN - 1);
#pragma clang loop unroll(disable)
      for (int t = lo; t <= hi; ++t) if (!used[t]) dirty[t] = 1;
    }
    __syncthreads();
#pragma clang loop unroll(disable)
    for (int t = tid; t < SLEN; t += 1024) {
      if (dirty[t]) { dirty[t] = 0; bestPair[t] = best_code<true>(simsT, used, t); }
    }
    __syncthreads();
  }

  int m = min(takenCnt, 2048);
#pragma clang loop unroll(disable)
  for (int k = tid; k < m; k += 1024) tcodeG[b * 2048 + k] = takenCode[k];
  if (tid == 0) tcntG[b] = m;
}

// K3b: top-r selection via 8-pass MSD radix select on sortable-u64 f64 keys.
// Selection set provably == {rank < r} under (sim desc, i asc, d asc): partition
// by key byte-by-byte; survivors after 8 passes share the FULL key (exact f64
// ties) and are resolved by code asc. Then compaction + metadata (r9-identical).
__global__ __launch_bounds__(1024) void k_rank(const double* __restrict__ simsT_all,
                                               const unsigned short* __restrict__ tcodeG,
                                               const int* __restrict__ tcntG,
                                               const float* __restrict__ norms,
                                               int* __restrict__ kt, int* __restrict__ pjr,
                                               float* __restrict__ wir, float* __restrict__ wjr,
                                               float* __restrict__ out_pos) {
  int b = blockIdx.x;
  const double* simsT = simsT_all + (size_t)b * SLEN * 16;
  __shared__ unsigned long long key[2048];
  __shared__ unsigned short code[2048];
  __shared__ unsigned char state[2048];     // 0 = candidate, 1 = accepted, 2 = rejected
  __shared__ unsigned int hist[256];
  __shared__ unsigned int bcum[256];        // # candidates in strictly-better buckets
  __shared__ unsigned int wsum[4];
  __shared__ int sharedB, sharedNeed, sdone, allAccept;
  __shared__ unsigned short memberIdx[2048];
  __shared__ int memberCnt;
  __shared__ unsigned char skipA[SLEN];
  __shared__ unsigned char mergeD[SLEN];
  __shared__ int wTot[16], wOff[16];
  int tid = threadIdx.x;
  int m = min(tcntG[b], 2048);
#pragma clang loop unroll(disable)
  for (int t = tid; t < SLEN; t += 1024) { skipA[t] = 0; mergeD[t] = 0; }
#pragma clang loop unroll(disable)
  for (int k = tid; k < m; k += 1024) {
    unsigned short c = tcodeG[b * 2048 + k];
    code[k] = c;
    state[k] = 0;
    double s = simsT[(size_t)(c >> 4) * 16 + (c & 15)];
    unsigned long long bits = (unsigned long long)__double_as_longlong(s);
    key[k] = (bits & 0x8000000000000000ULL) ? ~bits : (bits | 0x8000000000000000ULL);
  }
  if (tid == 0) { sharedNeed = RSEL; sdone = 0; allAccept = (m <= RSEL); memberCnt = 0; }
  __syncthreads();

  if (!allAccept) {
#pragma clang loop unroll(disable)
    for (int pass = 0; pass < 8; ++pass) {
      if (tid < 256) hist[tid] = 0;
      __syncthreads();
      int sh = 56 - 8 * pass;
#pragma clang loop unroll(disable)
      for (int k = tid; k < m; k += 1024)
        if (!state[k]) atomicAdd(&hist[(unsigned int)(key[k] >> sh) & 0xFFu], 1u);
      __syncthreads();
      // parallel suffix-sum (descending buckets) via wave shfl scan over 256 bins
      unsigned int v = 0, inc = 0;
      int lane = tid & 63, w = tid >> 6;
      if (tid < 256) {
        v = hist[255 - tid];
        inc = v;
        for (int o = 1; o < 64; o <<= 1) { unsigned int n = __shfl_up(inc, o, 64); if (lane >= o) inc += n; }
        if (lane == 63) wsum[w] = inc;
      }
      __syncthreads();
      if (tid < 256) {
        unsigned int off = 0;
        for (int ww = 0; ww < w; ++ww) off += wsum[ww];
        unsigned int incl = inc + off;
        bcum[255 - tid] = incl - v;          // candidates strictly better than this bucket
      }
      __syncthreads();
      if (tid < 256) {
        int bkt = 255 - tid;
        unsigned int ag = bcum[bkt];
        unsigned int need = (unsigned int)sharedNeed;
        if (ag < need && ag + hist[bkt] >= need) sharedB = bkt;   // unique straddle bucket
      }
      __syncthreads();
      int B = sharedB;
      unsigned int needInB = (unsigned int)sharedNeed - bcum[B];
#pragma clang loop unroll(disable)
      for (int k = tid; k < m; k += 1024) {
        if (!state[k]) {
          unsigned int bv = (unsigned int)(key[k] >> sh) & 0xFFu;
          if ((int)bv > B) state[k] = 1;
          else if ((int)bv < B) state[k] = 2;
        }
      }
      __syncthreads();
      if (tid == 0) {
        sharedNeed = (int)needInB;
        if (hist[B] == needInB) sdone = 1;   // straddle exactly fills: accept all remaining
      }
      __syncthreads();
      if (sdone) break;
    }
  }
  __syncthreads();

  if (allAccept || sdone) {
#pragma clang loop unroll(disable)
    for (int k = tid; k < m; k += 1024) if (!state[k]) state[k] = 1;
  } else {
    // survivors share the full 64-bit key (exact f64 ties): tie-break by code asc
#pragma clang loop unroll(disable)
    for (int k = tid; k < m; k += 1024)
      if (!state[k]) { int idx = atomicAdd(&memberCnt, 1); memberIdx[idx] = (unsigned short)k; }
    __syncthreads();
    int mc = memberCnt;
    unsigned int need = (unsigned int)sharedNeed;
#pragma clang loop unroll(disable)
    for (int z = tid; z < mc; z += 1024) {
      int k = memberIdx[z];
      unsigned short ck = code[k];
      unsigned int wr = 0;
#pragma clang loop unroll(disable)
      for (int q2 = 0; q2 < mc; ++q2) if (code[memberIdx[q2]] < ck) wr++;
      if (wr < need) state[k] = 1;
    }
  }
  __syncthreads();
  // mark selected pairs
#pragma clang loop unroll(disable)
  for (int k = tid; k < m; k += 1024) {
    if (state[k] == 1) {
      unsigned short ck = code[k];
      int i = ck >> 4, d = ck & 15;
      mergeD[i] = (unsigned char)d;
      skipA[i + d] = 1;
    }
  }
  __syncthreads();
  // compact kept tokens (prefix sum of !skip), 4 contiguous tokens per thread
  int cnt = 0; unsigned char kf[4];
  int tbase = tid * 4;
  for (int u = 0; u < 4; ++u) { kf[u] = skipA[tbase + u] ? 0 : 1; cnt += kf[u]; }
  int lane = tid & 63, wv = tid >> 6;
  int incl = cnt;
  for (int o = 1; o < 64; o <<= 1) { int n = __shfl_up(incl, o, 64); if (lane >= o) incl += n; }
  if (lane == 63) wTot[wv] = incl;
  __syncthreads();
  if (tid < 16) {
    int v2 = wTot[tid];
    for (int o = 1; o < 16; o <<= 1) { int n = __shfl_up(v2, o, 64); if (lane >= o) v2 += n; }
    wOff[tid] = v2 - wTot[tid];
  }
  __syncthreads();
  int pos = wOff[wv] + (incl - cnt);
  for (int u = 0; u < 4; ++u) {
    int t = tbase + u;
    if (kf[u]) {
      if (pos < KEEP) {
        int orow = b * KEEP + pos;
        kt[orow] = t;
        int d = mergeD[t];
        pjr[orow] = d ? (t + d) : -1;
        wir[orow] = norms[b * SLEN + t];
        wjr[orow] = d ? norms[b * SLEN + t + d] : 0.0f;
        out_pos[orow] = (float)(b * SLEN + t);
      }
      pos++;
    }
  }
}

// K4: x output rows (512 f32), weighted merge. Indices clamped: poison can never fault.
__global__ __launch_bounds__(128) void k_gather_x(const float* __restrict__ x,
                                                  const int* __restrict__ kt, const int* __restrict__ pjr,
                                                  const float* __restrict__ wir, const float* __restrict__ wjr,
                                                  float* __restrict__ outx) {
  int orow = blockIdx.x;
  int b = orow / KEEP;
  int t = kt[orow], pj = pjr[orow];
  int gi = min(max(b * SLEN + t, 0), NTOK - 1);
  const float4* xi = (const float4*)(x + (size_t)gi * DDIM);
  float4* o = (float4*)(outx + (size_t)orow * DDIM);
  int c = threadIdx.x;
  float4 v = xi[c];
  if (pj >= 0) {
    int gj = min(b * SLEN + min(pj, SLEN - 1), NTOK - 1);
    const float4* xj = (const float4*)(x + (size_t)gj * DDIM);
    float4 u = xj[c];
    float wi = wir[orow], wj = wjr[orow];
    float inv = 1.0f / (wi + wj + 1e-8f);
    v.x = (wi * v.x + wj * u.x) * inv;
    v.y = (wi * v.y + wj * u.y) * inv;
    v.z = (wi * v.z + wj * u.z) * inv;
    v.w = (wi * v.w + wj * u.w) * inv;
  }
  o[c] = v;
}

// K5: source output rows (4096 f32), plain sum merge — the BW-dominant kernel
__global__ __launch_bounds__(256) void k_gather_s(const float* __restrict__ src,
                                                  const int* __restrict__ kt, const int* __restrict__ pjr,
                                                  float* __restrict__ outs) {
  int orow = blockIdx.x;
  int b = orow / KEEP;
  int t = kt[orow], pj = pjr[orow];
  int gi = min(max(b * SLEN + t, 0), NTOK - 1);
  const float4* si = (const float4*)(src + (size_t)gi * NORIG);
  float4* o = (float4*)(outs + (size_t)orow * NORIG);
  if (pj >= 0) {
    int gj = min(b * SLEN + min(pj, SLEN - 1), NTOK - 1);
    const float4* sj = (const float4*)(src + (size_t)gj * NORIG);
    for (int u = 0; u < 4; ++u) {
      int c = threadIdx.x + u * 256;
      float4 a = si[c], bb = sj[c];
      a.x += bb.x; a.y += bb.y; a.z += bb.z; a.w += bb.w;
      o[c] = a;
    }
  } else {
    for (int u = 0; u < 4; ++u) { int c = threadIdx.x + u * 256; o[c] = si[c]; }
  }
}

extern "C" void kernel_launch(void* const* d_in, const int* in_sizes, int n_in,
                              void* d_out, int out_size, void* d_ws, size_t ws_size,
                              hipStream_t stream) {
  if (ws_size < WS_NEEDED) return;  // fail fast & clean instead of faulting

  const float* x = (const float*)d_in[0];
  const float* source = (const float*)d_in[1];
  // d_in[2] = position_ids (== arange(B*S)); d_in[3] = r (1024); d_in[4] = window_size (16)
  const float* Wm = (const float*)d_in[5];

  char* ws = (char*)d_ws;
  double* gn = (double*)(ws + OFF_GN);
  double* simsT = (double*)(ws + OFF_SIMST);
  float* norms = (float*)(ws + OFF_NORMS);
  unsigned short* best0 = (unsigned short*)(ws + OFF_BEST0);
  unsigned short* tcode = (unsigned short*)(ws + OFF_TCODE);  // reuses gn (dead after k_sims)
  int* tcnt = (int*)(ws + OFF_TCNT);
  int* kt = (int*)(ws + OFF_KT);
  int* pjr = (int*)(ws + OFF_PJR);
  float* wir = (float*)(ws + OFF_WIR);
  float* wjr = (float*)(ws + OFF_WJR);

  float* out = (float*)d_out;
  float* outx = out + OUTX_OFF;
  float* outs = out + OUTS_OFF;
  float* outp = out + OUTP_OFF;

  k_proj<<<(BATCH * SLEN) / 16, 256, 0, stream>>>(x, Wm, gn, norms);
  k_sims<<<BATCH * (SLEN / 64), 256, 0, stream>>>(gn, simsT);
  k_best0<<<NTOK / 256, 256, 0, stream>>>(simsT, best0);
  k_peel<<<BATCH, 1024, 0, stream>>>(simsT, best0, tcode, tcnt);
  k_rank<<<BATCH, 1024, 0, stream>>>(simsT, tcode, tcnt, norms, kt, pjr, wir, wjr, outp);
  k_gather_x<<<BATCH * KEEP, 128, 0, stream>>>(x, kt, pjr, wir, wjr, outx);
  k_gather_s<<<BATCH * KEEP, 256, 0, stream>>>(source, kt, pjr, outs);
}